// Round 17
// baseline (433.485 us; speedup 1.0000x reference)
//
#include <hip/hip_runtime.h>
#include <math.h>

// ---------------- static problem config ----------------
#define N_NODES   100000
#define N_GRAPHS  100
#define NPG       1000
#define N_EDGES   1600000
#define EPG       16000      // edges per graph
#define HID       16
#define HEADS     4
#define HD        64
#define OUT_DIM   10
#define BN_EPS    1e-5f
#define NEG_SLOPE 0.2f

#define LDA 68          // padded row stride for LDS tiles
#define BF_BLOCKS 782   // gemm_mfma_bf grid: 3128 waves -> 2 tiles/wave (amortized preamble)
#define PB_PER_GRAPH 5  // pool_bn blocks per graph
#define PB_NODES 200    // nodes per pool_bn block

// ---------------- workspace layout (float elements) ----------------
static const size_t OFF_SPART = 0;         // stats partials [BF_BLOCKS][128] (reused both layers)
static const size_t OFF_PEWS  = 7000000;   // 384 floats
static const size_t OFF_STAT1 = 7001000;   // 128 floats (layer-1 BN stats)
static const size_t OFF_WFRAG = 7010000;   // 2 layers x 4096 uints (fW bf16 MFMA fragments)
static const size_t OFF_WF2   = 7020000;   // 2 layers x 4096 uints (Wp/Wd bf16 MFMA B-fragments)
static const size_t OFF_POOL  = 7100000;   // pooled [100][64] ; pooledF0 at +6400
static const size_t OFF_HL    = 8000000;   // hl bf16 [N][128] = [N][64] uints
static const size_t OFF_CAT   = 20800000;  // gat_cat bf16 [N][128] = [N][64] uints
static const size_t OFF_F0    = 33600000;  // [N][64] fp32
static const size_t OFF_F1    = 40000000;  // [N][64]
static const size_t OFF_SPSP  = 46400000;  // sps plane-p [N*4]
static const size_t OFF_SPSD  = 46800000;  // sps plane-d [N*4]
static const size_t OFF_DPD   = 47200000;  // dpd float2 [N][4]  (d_p_adj, d_d)
static const size_t OFF_STATS = 48000000;  // 128 floats (layer-0 BN stats)
static const size_t OFF_CSR   = 48000128;  // ints
static const size_t OFF_SRT   = 48100144;  // ints

// ---------------- bf16 helpers (RNE pack, exact unpack) ----------------
__device__ inline unsigned bf_pack(float x, float y) {
    unsigned ux = __float_as_uint(x);
    unsigned uy = __float_as_uint(y);
    ux = (ux + 0x7FFFu + ((ux >> 16) & 1u)) >> 16;
    uy = ((uy + 0x7FFFu + ((uy >> 16) & 1u)) >> 16) << 16;
    return ux | uy;
}
__device__ inline float bf_lo(unsigned u) { return __uint_as_float(u << 16); }
__device__ inline float bf_hi(unsigned u) { return __uint_as_float(u & 0xFFFF0000u); }

// MFMA fragment types (gfx950: 16x16x32 bf16 -> 8 bf16 in, 4 f32 acc)
typedef __attribute__((ext_vector_type(8))) short bf16x8;
typedef __attribute__((ext_vector_type(4))) float f32x4;

__device__ inline bf16x8 frag_from(unsigned a, unsigned b, unsigned c, unsigned d) {
    uint4 u{a, b, c, d};
    return *reinterpret_cast<bf16x8*>(&u);
}

// ---------------- per-graph counting sort of edges by dst + merged prep ----------------
// Blocks 0..99: per-graph counting sort. Blocks 100..103: prep work (PE collapse,
// W fragments, zero-init) running concurrently -- saves one launch + serialization.
__global__ __launch_bounds__(1024) void sort_prep(const int* __restrict__ ei,
                                                  int* __restrict__ csr_off,
                                                  int* __restrict__ sorted_src,
                                                  const float* __restrict__ peW, const float* __restrict__ peb,
                                                  const float* __restrict__ pW0, const float* __restrict__ dW0,
                                                  const float* __restrict__ pW1, const float* __restrict__ dW1,
                                                  const float* __restrict__ fW0, const float* __restrict__ fW1,
                                                  float* __restrict__ pe,
                                                  uint4* __restrict__ wfA,
                                                  uint4* __restrict__ wfD,
                                                  float* __restrict__ pool2,
                                                  float* __restrict__ stats0,
                                                  float* __restrict__ stats1) {
    const int g = blockIdx.x;
    const int t = threadIdx.x;
    if (g >= N_GRAPHS) {
        const int b = g - N_GRAPHS;
        if (b == 0) {
            if (t < 128) {
                int r = t >> 6, c = t & 63;
                float sp = 0.f, sd = 0.f;
                for (int m = 0; m < 16; ++m) {
                    sp += peW[r * 16 + m] * pW0[(64 + m) * 64 + c];
                    sd += peW[r * 16 + m] * dW0[(64 + m) * 64 + c];
                }
                pe[r * 64 + c] = sp;
                pe[192 + r * 64 + c] = sd;
            } else if (t < 192) {
                int c = t & 63;
                float sp = 0.f, sd = 0.f;
                for (int m = 0; m < 16; ++m) {
                    sp += peb[m] * pW0[(64 + m) * 64 + c];
                    sd += peb[m] * dW0[(64 + m) * 64 + c];
                }
                pe[128 + c] = sp;
                pe[320 + c] = sd;
            }
        } else if (b == 1) {
            if (t < 256)
            for (int i = t; i < 2 * 4 * 4 * 64; i += 256) {
                const int lane  = i & 63;
                const int ct    = (i >> 6) & 3;
                const int kk    = (i >> 8) & 3;
                const int layer = i >> 10;
                const float* W = layer ? fW1 : fW0;
                const int col = ct * 16 + (lane & 15);
                const int kb  = kk * 32 + (lane >> 4) * 8;
                uint4 u;
                u.x = bf_pack(W[(kb + 0) * 64 + col], W[(kb + 1) * 64 + col]);
                u.y = bf_pack(W[(kb + 2) * 64 + col], W[(kb + 3) * 64 + col]);
                u.z = bf_pack(W[(kb + 4) * 64 + col], W[(kb + 5) * 64 + col]);
                u.w = bf_pack(W[(kb + 6) * 64 + col], W[(kb + 7) * 64 + col]);
                wfA[i] = u;
            }
        } else if (b == 2) {
            if (t < 256)
            for (int i = t; i < 2048; i += 256) {
                const int lane  = i & 63;
                const int ct    = (i >> 6) & 3;
                const int kk    = (i >> 8) & 1;
                const int mat   = (i >> 9) & 1;
                const int layer = i >> 10;
                const float* W = layer ? (mat ? dW1 : pW1) : (mat ? dW0 : pW0);
                const int col = ct * 16 + (lane & 15);
                const int kb  = kk * 32 + (lane >> 4) * 8;
                uint4 u;
                u.x = bf_pack(W[(kb + 0) * 64 + col], W[(kb + 1) * 64 + col]);
                u.y = bf_pack(W[(kb + 2) * 64 + col], W[(kb + 3) * 64 + col]);
                u.z = bf_pack(W[(kb + 4) * 64 + col], W[(kb + 5) * 64 + col]);
                u.w = bf_pack(W[(kb + 6) * 64 + col], W[(kb + 7) * 64 + col]);
                wfD[i] = u;
            }
        } else {
            for (int i = t; i < 2 * N_GRAPHS * 64; i += 1024) pool2[i] = 0.f;
            if (t < 128) { stats0[t] = 0.f; stats1[t] = 0.f; }
        }
        return;
    }

    __shared__ int hist[1024];
    __shared__ int scan[1024];
    const int* src = ei;
    const int* dst = ei + N_EDGES;
    const int e0 = g * EPG;
    const int nbase = g * NPG;

    hist[t] = 0;
    __syncthreads();
    for (int i = t; i < EPG; i += 1024) {
        int d = dst[e0 + i] - nbase;
        atomicAdd(&hist[d], 1);
    }
    __syncthreads();
    scan[t] = hist[t];
    __syncthreads();
    for (int off = 1; off < 1024; off <<= 1) {
        int v = (t >= off) ? scan[t - off] : 0;
        __syncthreads();
        scan[t] += v;
        __syncthreads();
    }
    int excl = scan[t] - hist[t];
    if (t < NPG) csr_off[nbase + t] = e0 + excl;
    if (g == 0 && t == 0) csr_off[N_NODES] = N_EDGES;
    __syncthreads();
    hist[t] = excl;
    __syncthreads();
    for (int i = t; i < EPG; i += 1024) {
        int s = src[e0 + i];
        int d = dst[e0 + i] - nbase;
        int slot = atomicAdd(&hist[d], 1);
        sorted_src[e0 + slot] = s;
    }
}

// ---------------- stats partial reduction: spart[nb][128] -> stats[128] ----------------
__global__ __launch_bounds__(128) void reduce_stats(const float* __restrict__ part,
                                                    float* __restrict__ stats, int nb) {
    const int c = threadIdx.x;           // 0..127
    const int per = (nb + gridDim.x - 1) / gridDim.x;
    const int b0 = blockIdx.x * per;
    int b1 = b0 + per; if (b1 > nb) b1 = nb;
    float s = 0.f;
    for (int b = b0; b < b1; ++b) s += part[(size_t)b * 128 + c];
    atomicAdd(&stats[c], s);
}

// ---------------- MFMA dual GEMM (K=64) + fused attention-logit epilogue ----------------
// A (f32) split hi/lo bf16 in registers; W bf16. 32 MFMA per 16-node wave-tile.
// LDS HALVED (34816->17408B): the p/d accumulator planes share ONE buffer
// sequentially (scatter p -> barrier -> read p -> barrier -> scatter d -> barrier
// -> read d). Raises the occupancy cap from LDS-bound 16 waves/CU to VGPR-bound
// 24 waves/CU at the cost of 2 extra barriers; values are bit-identical.
// NOTE (R15): 2-tiles/block + hoisted preamble regressed (VGPR 84->108); 1 tile/block.
template <bool PE, bool BN>
__global__ __launch_bounds__(256) void gemm_dual_mfma(const float* __restrict__ A,
                                                      const unsigned* __restrict__ wf2,
                                                      const float* __restrict__ pe,
                                                      const float* __restrict__ pas,
                                                      const float* __restrict__ pad_,
                                                      const float* __restrict__ das,
                                                      const float* __restrict__ dad,
                                                      const float* __restrict__ posW,
                                                      const float* __restrict__ posb,
                                                      const float* __restrict__ stats,
                                                      const float* __restrict__ gamma,
                                                      const float* __restrict__ beta,
                                                      float* __restrict__ poolF,
                                                      unsigned* __restrict__ hl,
                                                      float* __restrict__ sps_p,
                                                      float* __restrict__ sps_d,
                                                      float2* __restrict__ dpd) {
    __shared__ float sD[4 * 16 * LDA];   // [wave][row][LDA] single plane = 17408 B
    const int t = threadIdx.x;
    const int w = t >> 6, lane = t & 63;
    const int cidx = lane & 15, khi = lane >> 4;
    const int node0 = blockIdx.x * 64;

    // preload W fragments [mat][kk][ct]
    bf16x8 wf[2][2][4];
#pragma unroll
    for (int mat = 0; mat < 2; ++mat)
#pragma unroll
        for (int kk = 0; kk < 2; ++kk)
#pragma unroll
            for (int ct = 0; ct < 4; ++ct)
                wf[mat][kk][ct] = *reinterpret_cast<const bf16x8*>(
                    wf2 + (size_t)((((mat * 2 + kk) * 4 + ct) * 64) + lane) * 4);

    // load A row (BN path: normalize+ELU+pool), build hi/lo fragments
    const int node0w = node0 + w * 16;
    int gn = node0w + cidx; if (gn > N_NODES - 1) gn = N_NODES - 1;
    const float* ar = A + (size_t)gn * 64;
    bf16x8 ah[2], al[2];
#pragma unroll
    for (int kk = 0; kk < 2; ++kk) {
        const int k0 = kk * 32 + khi * 8;
        float4 f0 = *reinterpret_cast<const float4*>(ar + k0);
        float4 f1 = *reinterpret_cast<const float4*>(ar + k0 + 4);
        if (BN) {
            const float invN = 1.0f / (float)N_NODES;
            float4 sa = *reinterpret_cast<const float4*>(&stats[k0]);
            float4 sb = *reinterpret_cast<const float4*>(&stats[k0 + 4]);
            float4 qa = *reinterpret_cast<const float4*>(&stats[64 + k0]);
            float4 qb = *reinterpret_cast<const float4*>(&stats[64 + k0 + 4]);
            float4 ga = *reinterpret_cast<const float4*>(&gamma[k0]);
            float4 gb = *reinterpret_cast<const float4*>(&gamma[k0 + 4]);
            float4 ba = *reinterpret_cast<const float4*>(&beta[k0]);
            float4 bb = *reinterpret_cast<const float4*>(&beta[k0 + 4]);
            float sc[8], sh[8];
            float ss[8] = {sa.x, sa.y, sa.z, sa.w, sb.x, sb.y, sb.z, sb.w};
            float qq[8] = {qa.x, qa.y, qa.z, qa.w, qb.x, qb.y, qb.z, qb.w};
            float gg[8] = {ga.x, ga.y, ga.z, ga.w, gb.x, gb.y, gb.z, gb.w};
            float bt[8] = {ba.x, ba.y, ba.z, ba.w, bb.x, bb.y, bb.z, bb.w};
#pragma unroll
            for (int i = 0; i < 8; ++i) {
                float mu = ss[i] * invN;
                float var = qq[i] * invN - mu * mu;
                float iv = rsqrtf(var + BN_EPS);
                sc[i] = iv * gg[i];
                sh[i] = bt[i] - mu * sc[i];
            }
            auto ap = [&](float v, int i) {
                float r = fmaf(v, sc[i], sh[i]);
                return r > 0.f ? r : (__expf(r) - 1.f);
            };
            f0.x = ap(f0.x, 0); f0.y = ap(f0.y, 1); f0.z = ap(f0.z, 2); f0.w = ap(f0.w, 3);
            f1.x = ap(f1.x, 4); f1.y = ap(f1.y, 5); f1.z = ap(f1.z, 6); f1.w = ap(f1.w, 7);
            // per-graph pooling of transformed values (Σ over nodes)
            if (node0w < N_NODES) {
                const int node_l = node0w + cidx;
                const bool okn = node_l < N_NODES;
                const int gl = node_l / NPG;
                const int g0 = node0w / NPG;
                int lastn = node0w + 15; if (lastn > N_NODES - 1) lastn = N_NODES - 1;
                const int g1 = lastn / NPG;
                float p8[8] = {f0.x, f0.y, f0.z, f0.w, f1.x, f1.y, f1.z, f1.w};
                {
                    const bool m = okn && (gl == g0);
#pragma unroll
                    for (int i = 0; i < 8; ++i) {
                        float tv = m ? p8[i] : 0.f;
                        tv += __shfl_xor(tv, 1); tv += __shfl_xor(tv, 2);
                        tv += __shfl_xor(tv, 4); tv += __shfl_xor(tv, 8);
                        if (cidx == 0) atomicAdd(&poolF[g0 * 64 + k0 + i], tv);
                    }
                }
                if (g1 != g0) {
                    const bool m = okn && (gl == g1);
#pragma unroll
                    for (int i = 0; i < 8; ++i) {
                        float tv = m ? p8[i] : 0.f;
                        tv += __shfl_xor(tv, 1); tv += __shfl_xor(tv, 2);
                        tv += __shfl_xor(tv, 4); tv += __shfl_xor(tv, 8);
                        if (cidx == 0) atomicAdd(&poolF[g1 * 64 + k0 + i], tv);
                    }
                }
            }
        }
        unsigned h0 = bf_pack(f0.x, f0.y), h1 = bf_pack(f0.z, f0.w);
        unsigned h2 = bf_pack(f1.x, f1.y), h3 = bf_pack(f1.z, f1.w);
        unsigned l0 = bf_pack(f0.x - bf_lo(h0), f0.y - bf_hi(h0));
        unsigned l1 = bf_pack(f0.z - bf_lo(h1), f0.w - bf_hi(h1));
        unsigned l2 = bf_pack(f1.x - bf_lo(h2), f1.y - bf_hi(h2));
        unsigned l3 = bf_pack(f1.z - bf_lo(h3), f1.w - bf_hi(h3));
        ah[kk] = frag_from(h0, h1, h2, h3);
        al[kk] = frag_from(l0, l1, l2, l3);
    }

    f32x4 ap4[4], ad4[4];
#pragma unroll
    for (int ct = 0; ct < 4; ++ct) { ap4[ct] = 0.f; ad4[ct] = 0.f; }
#pragma unroll
    for (int ct = 0; ct < 4; ++ct) {
        ap4[ct] = __builtin_amdgcn_mfma_f32_16x16x32_bf16(ah[0], wf[0][0][ct], ap4[ct], 0, 0, 0);
        ap4[ct] = __builtin_amdgcn_mfma_f32_16x16x32_bf16(ah[1], wf[0][1][ct], ap4[ct], 0, 0, 0);
        ap4[ct] = __builtin_amdgcn_mfma_f32_16x16x32_bf16(al[0], wf[0][0][ct], ap4[ct], 0, 0, 0);
        ap4[ct] = __builtin_amdgcn_mfma_f32_16x16x32_bf16(al[1], wf[0][1][ct], ap4[ct], 0, 0, 0);
        ad4[ct] = __builtin_amdgcn_mfma_f32_16x16x32_bf16(ah[0], wf[1][0][ct], ad4[ct], 0, 0, 0);
        ad4[ct] = __builtin_amdgcn_mfma_f32_16x16x32_bf16(ah[1], wf[1][1][ct], ad4[ct], 0, 0, 0);
        ad4[ct] = __builtin_amdgcn_mfma_f32_16x16x32_bf16(al[0], wf[1][0][ct], ad4[ct], 0, 0, 0);
        ad4[ct] = __builtin_amdgcn_mfma_f32_16x16x32_bf16(al[1], wf[1][1][ct], ad4[ct], 0, 0, 0);
    }

    const int tx = t & 15, ty = t >> 4;
    const int c4 = tx * 4;
    float4 accp[4], accd[4];

    // ---- plane p: scatter -> barrier -> read -> barrier ----
    {
        float* base = sD + w * (16 * LDA);
#pragma unroll
        for (int ct = 0; ct < 4; ++ct)
#pragma unroll
            for (int q = 0; q < 4; ++q)
                base[(khi * 4 + q) * LDA + ct * 16 + cidx] = ap4[ct][q];
    }
    __syncthreads();
#pragma unroll
    for (int j = 0; j < 4; ++j) {
        const int n = ty * 4 + j;
        accp[j] = *reinterpret_cast<const float4*>(sD + (n >> 4) * (16 * LDA) + (n & 15) * LDA + c4);
    }
    __syncthreads();

    // ---- plane d: scatter -> barrier -> read ----
    {
        float* base = sD + w * (16 * LDA);
#pragma unroll
        for (int ct = 0; ct < 4; ++ct)
#pragma unroll
            for (int q = 0; q < 4; ++q)
                base[(khi * 4 + q) * LDA + ct * 16 + cidx] = ad4[ct][q];
    }
    __syncthreads();
#pragma unroll
    for (int j = 0; j < 4; ++j) {
        const int n = ty * 4 + j;
        accd[j] = *reinterpret_cast<const float4*>(sD + (n >> 4) * (16 * LDA) + (n & 15) * LDA + c4);
    }

    if (PE) {
        float4 pp0 = *reinterpret_cast<const float4*>(&pe[c4]);
        float4 pp1 = *reinterpret_cast<const float4*>(&pe[64 + c4]);
        float4 ppb = *reinterpret_cast<const float4*>(&pe[128 + c4]);
        float4 pd0 = *reinterpret_cast<const float4*>(&pe[192 + c4]);
        float4 pd1 = *reinterpret_cast<const float4*>(&pe[256 + c4]);
        float4 pdb = *reinterpret_cast<const float4*>(&pe[320 + c4]);
#pragma unroll
        for (int j = 0; j < 4; ++j) {
            int node = node0 + ty * 4 + j;
            int r = node % NPG;
            float px = (float)(r >> 5) * (1.0f / 31.0f);
            float py = (float)(r & 31) * (1.0f / 31.0f);
            accp[j].x += px * pp0.x + py * pp1.x + ppb.x;
            accp[j].y += px * pp0.y + py * pp1.y + ppb.y;
            accp[j].z += px * pp0.z + py * pp1.z + ppb.z;
            accp[j].w += px * pp0.w + py * pp1.w + ppb.w;
            accd[j].x += px * pd0.x + py * pd1.x + pdb.x;
            accd[j].y += px * pd0.y + py * pd1.y + pdb.y;
            accd[j].z += px * pd0.z + py * pd1.z + pdb.z;
            accd[j].w += px * pd0.w + py * pd1.w + pdb.w;
        }
    }

    float4 pasv = *reinterpret_cast<const float4*>(&pas[c4]);
    float4 padv = *reinterpret_cast<const float4*>(&pad_[c4]);
    float4 dasv = *reinterpret_cast<const float4*>(&das[c4]);
    float4 dadv = *reinterpret_cast<const float4*>(&dad[c4]);
    const int h = tx >> 2;
    const float pw0 = posW[h], pw1 = posW[4 + h], pb = posb[h];
    const int cu = tx * 2;   // uint index within 64-uint row
#pragma unroll
    for (int j = 0; j < 4; ++j) {
        const int node = node0 + ty * 4 + j;
        float vps = accp[j].x * pasv.x + accp[j].y * pasv.y + accp[j].z * pasv.z + accp[j].w * pasv.w;
        float vpd = accp[j].x * padv.x + accp[j].y * padv.y + accp[j].z * padv.z + accp[j].w * padv.w;
        float vds = accd[j].x * dasv.x + accd[j].y * dasv.y + accd[j].z * dasv.z + accd[j].w * dasv.w;
        float vdd = accd[j].x * dadv.x + accd[j].y * dadv.y + accd[j].z * dadv.z + accd[j].w * dadv.w;
        vps += __shfl_xor(vps, 1); vps += __shfl_xor(vps, 2);
        vpd += __shfl_xor(vpd, 1); vpd += __shfl_xor(vpd, 2);
        vds += __shfl_xor(vds, 1); vds += __shfl_xor(vds, 2);
        vdd += __shfl_xor(vdd, 1); vdd += __shfl_xor(vdd, 2);
        if (node < N_NODES) {
            uint2 up, ud;
            up.x = bf_pack(accp[j].x, accp[j].y); up.y = bf_pack(accp[j].z, accp[j].w);
            ud.x = bf_pack(accd[j].x, accd[j].y); ud.y = bf_pack(accd[j].z, accd[j].w);
            *reinterpret_cast<uint2*>(&hl[(size_t)node * 64 + cu])      = up;
            *reinterpret_cast<uint2*>(&hl[(size_t)node * 64 + 32 + cu]) = ud;
            if ((tx & 3) == 0) {
                const int r = node % NPG;
                const float pxn = (float)(r >> 5) * (1.0f / 31.0f);
                const float pyn = (float)(r & 31) * (1.0f / 31.0f);
                const float posdot = pxn * pw0 + pyn * pw1;
                sps_p[node * 4 + h] = vps - posdot;
                sps_d[node * 4 + h] = vds;
                dpd[node * 4 + h] = float2{vpd + posdot + pb, vdd};
            }
        }
    }
}

// ---------------- MFMA GEMM: out = bf16A[N,128] @ Wbf[128,64] + b, + BN stat partials ----------------
__global__ __launch_bounds__(256) void gemm_mfma_bf(const unsigned* __restrict__ A,
                                                    const unsigned* __restrict__ wfrag,
                                                    const float* __restrict__ bias,
                                                    float* __restrict__ out,
                                                    float* __restrict__ spart) {
    __shared__ float red[512];
    const int t = threadIdx.x;
    const int lane = t & 63;
    const int cidx = lane & 15;   // A-frag row within tile; D col within col-tile
    const int khi  = lane >> 4;   // k-group for A/B frags; D row-group

    bf16x8 wf[4][4];
#pragma unroll
    for (int kk = 0; kk < 4; ++kk)
#pragma unroll
        for (int ct = 0; ct < 4; ++ct)
            wf[kk][ct] = *reinterpret_cast<const bf16x8*>(wfrag + (size_t)((kk * 4 + ct) * 64 + lane) * 4);

    float bias_r[4];
#pragma unroll
    for (int ct = 0; ct < 4; ++ct) bias_r[ct] = bias[ct * 16 + cidx];

    float ls[4] = {0.f, 0.f, 0.f, 0.f};
    float lq[4] = {0.f, 0.f, 0.f, 0.f};

    const int NW  = gridDim.x << 2;
    const int wid = (blockIdx.x << 2) + (t >> 6);
    for (int tile = wid; tile < N_NODES / 16; tile += NW) {
        const int node0 = tile << 4;
        const unsigned* arow = A + (size_t)(node0 + cidx) * 64 + khi * 4;
        bf16x8 a0 = *reinterpret_cast<const bf16x8*>(arow);
        bf16x8 a1 = *reinterpret_cast<const bf16x8*>(arow + 16);
        bf16x8 a2 = *reinterpret_cast<const bf16x8*>(arow + 32);
        bf16x8 a3 = *reinterpret_cast<const bf16x8*>(arow + 48);

        f32x4 acc[4];
#pragma unroll
        for (int ct = 0; ct < 4; ++ct) acc[ct] = 0.f;
#pragma unroll
        for (int ct = 0; ct < 4; ++ct) {
            acc[ct] = __builtin_amdgcn_mfma_f32_16x16x32_bf16(a0, wf[0][ct], acc[ct], 0, 0, 0);
            acc[ct] = __builtin_amdgcn_mfma_f32_16x16x32_bf16(a1, wf[1][ct], acc[ct], 0, 0, 0);
            acc[ct] = __builtin_amdgcn_mfma_f32_16x16x32_bf16(a2, wf[2][ct], acc[ct], 0, 0, 0);
            acc[ct] = __builtin_amdgcn_mfma_f32_16x16x32_bf16(a3, wf[3][ct], acc[ct], 0, 0, 0);
        }

        const int nbase = node0 + (khi << 2);
#pragma unroll
        for (int ct = 0; ct < 4; ++ct) {
#pragma unroll
            for (int q = 0; q < 4; ++q) {
                float v = acc[ct][q] + bias_r[ct];
                out[(size_t)(nbase + q) * 64 + ct * 16 + cidx] = v;
                ls[ct] += v;
                lq[ct] = fmaf(v, v, lq[ct]);
            }
        }
    }

#pragma unroll
    for (int ct = 0; ct < 4; ++ct) {
        ls[ct] += __shfl_xor(ls[ct], 16); ls[ct] += __shfl_xor(ls[ct], 32);
        lq[ct] += __shfl_xor(lq[ct], 16); lq[ct] += __shfl_xor(lq[ct], 32);
    }
    if (lane < 16) {
        const int w = t >> 6;
#pragma unroll
        for (int ct = 0; ct < 4; ++ct) {
            red[w * 64 + ct * 16 + lane]       = ls[ct];
            red[256 + w * 64 + ct * 16 + lane] = lq[ct];
        }
    }
    __syncthreads();
    if (t < 64) {
        float s  = red[t] + red[64 + t] + red[128 + t] + red[192 + t];
        float sq = red[256 + t] + red[320 + t] + red[384 + t] + red[448 + t];
        spart[(size_t)blockIdx.x * 128 + t]      = s;
        spart[(size_t)blockIdx.x * 128 + 64 + t] = sq;
    }
}

// ---------------- fused dual-GAT, cooperative weights, batched gathers ----------------
// Remainder chunk uses the SAME straight-line 8-wide batch as the main loop:
// phase-1 masks w=0 for lanes j1>=nj and the gather index is clamped to a valid
// edge, so shuffled weights for jj>=nj are exactly 0.0 and the extra FMAs are
// bit-exact no-ops.
__global__ __launch_bounds__(256) void gat_fused(const unsigned* __restrict__ hl,
                                                 const float* __restrict__ sps_p,
                                                 const float* __restrict__ sps_d,
                                                 const float2* __restrict__ dpd,
                                                 const int* __restrict__ csr_off,
                                                 const int* __restrict__ sorted_src,
                                                 unsigned* __restrict__ gat_cat) {
    const int b = blockIdx.x;
    const int logical = (b & 7) * 3125 + (b >> 3);   // XCD-aware swizzle
    const int v = logical * 4 + (threadIdx.x >> 6);
    if (v >= N_NODES) return;
    const int lane = threadIdx.x & 63;
    const int j1 = lane >> 3;
    const int p1 = (lane >> 2) & 1;
    const int h1 = lane & 3;
    const int phneed = ((lane >> 5) << 2) | ((lane & 31) >> 3);

    const float* __restrict__ spl = p1 ? sps_d : sps_p;
    const float2 dv1 = dpd[(size_t)v * 4 + h1];
    const float dval1 = p1 ? dv1.y : dv1.x;

    const int beg = __builtin_amdgcn_readfirstlane(csr_off[v]);
    const int end = __builtin_amdgcn_readfirstlane(csr_off[v + 1]);

    float2 acc = {0.f, 0.f};
    float wpart = 0.f;
    int e = beg;
    const int nfull = (end - beg) >> 3;

    int sA = 0, sB = 0;
    float svA = 0.f, svB = 0.f;
    if (nfull >= 1) { sA = sorted_src[e + j1]; svA = spl[(size_t)sA * 4 + h1]; }
    if (nfull >= 2) { sB = sorted_src[e + 8 + j1]; }

    for (int k = 0; k < nfull; ++k, e += 8) {
        int sC = 0;
        if (k + 2 < nfull) sC = sorted_src[e + 16 + j1];
        if (k + 1 < nfull) svB = spl[(size_t)sB * 4 + h1];
        float w = svA + dval1;
        w = fmaxf(w, NEG_SLOPE * w);
        w = __expf(w);
        wpart += w;
        // broadcast src rows + class weights
        int sj0 = __builtin_amdgcn_readlane(sA, 0);
        int sj1 = __builtin_amdgcn_readlane(sA, 8);
        int sj2 = __builtin_amdgcn_readlane(sA, 16);
        int sj3 = __builtin_amdgcn_readlane(sA, 24);
        int sj4 = __builtin_amdgcn_readlane(sA, 32);
        int sj5 = __builtin_amdgcn_readlane(sA, 40);
        int sj6 = __builtin_amdgcn_readlane(sA, 48);
        int sj7 = __builtin_amdgcn_readlane(sA, 56);
        float wj0 = __shfl(w, 0 + phneed);
        float wj1 = __shfl(w, 8 + phneed);
        float wj2 = __shfl(w, 16 + phneed);
        float wj3 = __shfl(w, 24 + phneed);
        float wj4 = __shfl(w, 32 + phneed);
        float wj5 = __shfl(w, 40 + phneed);
        float wj6 = __shfl(w, 48 + phneed);
        float wj7 = __shfl(w, 56 + phneed);
        // issue all gathers up front
        unsigned u0 = hl[((size_t)sj0 << 6) + lane];
        unsigned u1 = hl[((size_t)sj1 << 6) + lane];
        unsigned u2 = hl[((size_t)sj2 << 6) + lane];
        unsigned u3 = hl[((size_t)sj3 << 6) + lane];
        unsigned u4 = hl[((size_t)sj4 << 6) + lane];
        unsigned u5 = hl[((size_t)sj5 << 6) + lane];
        unsigned u6 = hl[((size_t)sj6 << 6) + lane];
        unsigned u7 = hl[((size_t)sj7 << 6) + lane];
        acc.x = fmaf(wj0, bf_lo(u0), acc.x); acc.y = fmaf(wj0, bf_hi(u0), acc.y);
        acc.x = fmaf(wj1, bf_lo(u1), acc.x); acc.y = fmaf(wj1, bf_hi(u1), acc.y);
        acc.x = fmaf(wj2, bf_lo(u2), acc.x); acc.y = fmaf(wj2, bf_hi(u2), acc.y);
        acc.x = fmaf(wj3, bf_lo(u3), acc.x); acc.y = fmaf(wj3, bf_hi(u3), acc.y);
        acc.x = fmaf(wj4, bf_lo(u4), acc.x); acc.y = fmaf(wj4, bf_hi(u4), acc.y);
        acc.x = fmaf(wj5, bf_lo(u5), acc.x); acc.y = fmaf(wj5, bf_hi(u5), acc.y);
        acc.x = fmaf(wj6, bf_lo(u6), acc.x); acc.y = fmaf(wj6, bf_hi(u6), acc.y);
        acc.x = fmaf(wj7, bf_lo(u7), acc.x); acc.y = fmaf(wj7, bf_hi(u7), acc.y);
        sA = sB; sB = sC; svA = svB;
    }

    if (e < end) {
        const int nj = end - e;
        int ee = e + j1; if (ee >= end) ee = end - 1;
        int s = sorted_src[ee];
        float sval = spl[(size_t)s * 4 + h1];
        float w = sval + dval1;
        w = fmaxf(w, NEG_SLOPE * w);
        w = __expf(w);
        if (j1 >= nj) w = 0.f;
        wpart += w;
        // full 8-wide batch (weights for jj>=nj are exactly 0; clamped gathers valid)
        int sj0 = __builtin_amdgcn_readlane(s, 0);
        int sj1 = __builtin_amdgcn_readlane(s, 8);
        int sj2 = __builtin_amdgcn_readlane(s, 16);
        int sj3 = __builtin_amdgcn_readlane(s, 24);
        int sj4 = __builtin_amdgcn_readlane(s, 32);
        int sj5 = __builtin_amdgcn_readlane(s, 40);
        int sj6 = __builtin_amdgcn_readlane(s, 48);
        int sj7 = __builtin_amdgcn_readlane(s, 56);
        float wj0 = __shfl(w, 0 + phneed);
        float wj1 = __shfl(w, 8 + phneed);
        float wj2 = __shfl(w, 16 + phneed);
        float wj3 = __shfl(w, 24 + phneed);
        float wj4 = __shfl(w, 32 + phneed);
        float wj5 = __shfl(w, 40 + phneed);
        float wj6 = __shfl(w, 48 + phneed);
        float wj7 = __shfl(w, 56 + phneed);
        unsigned u0 = hl[((size_t)sj0 << 6) + lane];
        unsigned u1 = hl[((size_t)sj1 << 6) + lane];
        unsigned u2 = hl[((size_t)sj2 << 6) + lane];
        unsigned u3 = hl[((size_t)sj3 << 6) + lane];
        unsigned u4 = hl[((size_t)sj4 << 6) + lane];
        unsigned u5 = hl[((size_t)sj5 << 6) + lane];
        unsigned u6 = hl[((size_t)sj6 << 6) + lane];
        unsigned u7 = hl[((size_t)sj7 << 6) + lane];
        acc.x = fmaf(wj0, bf_lo(u0), acc.x); acc.y = fmaf(wj0, bf_hi(u0), acc.y);
        acc.x = fmaf(wj1, bf_lo(u1), acc.x); acc.y = fmaf(wj1, bf_hi(u1), acc.y);
        acc.x = fmaf(wj2, bf_lo(u2), acc.x); acc.y = fmaf(wj2, bf_hi(u2), acc.y);
        acc.x = fmaf(wj3, bf_lo(u3), acc.x); acc.y = fmaf(wj3, bf_hi(u3), acc.y);
        acc.x = fmaf(wj4, bf_lo(u4), acc.x); acc.y = fmaf(wj4, bf_hi(u4), acc.y);
        acc.x = fmaf(wj5, bf_lo(u5), acc.x); acc.y = fmaf(wj5, bf_hi(u5), acc.y);
        acc.x = fmaf(wj6, bf_lo(u6), acc.x); acc.y = fmaf(wj6, bf_hi(u6), acc.y);
        acc.x = fmaf(wj7, bf_lo(u7), acc.x); acc.y = fmaf(wj7, bf_hi(u7), acc.y);
    }
    wpart += __shfl_xor(wpart, 8);
    wpart += __shfl_xor(wpart, 16);
    wpart += __shfl_xor(wpart, 32);
    const float wsum = __shfl(wpart, phneed);
    const float inv = 1.0f / (wsum + 1e-16f);
    gat_cat[(size_t)v * 64 + lane] = bf_pack(acc.x * inv, acc.y * inv);
}

// ---------------- BN + ELU + graph pooling, chain-free ----------------
__global__ __launch_bounds__(256) void pool_bn(const float* __restrict__ F, const float* __restrict__ stats,
                                               const float* __restrict__ gamma, const float* __restrict__ beta,
                                               float* __restrict__ pooled) {
    __shared__ float red[256];
    const int b = blockIdx.x;
    const int g = b / PB_PER_GRAPH;
    const int n0 = g * NPG + (b % PB_PER_GRAPH) * PB_NODES;
    const int t = threadIdx.x;
    const int c = t & 63, rg = t >> 6;
    const float mu = stats[c] * (1.0f / (float)N_NODES);
    const float var = stats[64 + c] * (1.0f / (float)N_NODES) - mu * mu;
    const float iv = rsqrtf(var + BN_EPS);
    const float sc = iv * gamma[c];
    const float sh = beta[c] - mu * sc;
    float s = 0.f;
    for (int i = rg; i < PB_NODES; i += 4) {
        float v = fmaf(F[(size_t)(n0 + i) * 64 + c], sc, sh);
        v = (v > 0.f) ? v : expm1f(v);
        s += v;
    }
    red[t] = s;
    __syncthreads();
    if (t < 64)
        atomicAdd(&pooled[g * 64 + c], red[c] + red[64 + c] + red[128 + c] + red[192 + c]);
}

// ---------------- task head: one wave per graph, residual folded in via pooled F0 ----------------
__global__ __launch_bounds__(64) void task_head(const float* __restrict__ pooled,
                                                const float* __restrict__ pooledF0,
                                                const float* __restrict__ resW,
                                                const float* __restrict__ resb,
                                                const float* __restrict__ taskW,
                                                const float* __restrict__ taskb,
                                                float* __restrict__ out) {
    const int g = blockIdx.x;
    const int c = threadIdx.x;
    float rc = 0.f;
    const float* pf = pooledF0 + g * 64;
    for (int k = 0; k < 64; ++k)
        rc = fmaf(pf[k], resW[k * 64 + c], rc);
    float p = (pooled[g * 64 + c] + rc) * (1.0f / (float)NPG) + resb[c];
#pragma unroll
    for (int o = 0; o < OUT_DIM; ++o) {
        float partial = p * taskW[c * OUT_DIM + o];
#pragma unroll
        for (int m = 1; m < 64; m <<= 1) partial += __shfl_xor(partial, m);
        if (c == 0) out[g * OUT_DIM + o] = partial + taskb[o];
    }
}

// ---------------- head-diversity loss for both layers ----------------
__global__ __launch_bounds__(256) void div_loss(const float* __restrict__ dW0,
                                                const float* __restrict__ dW1,
                                                float* __restrict__ out) {
    __shared__ float red[16][16];
    float total = 0.f;
    for (int layer = 0; layer < 2; ++layer) {
        const float* W = layer ? dW1 : dW0;
        const int din = layer ? 64 : 80;
        const int p = threadIdx.x & 15;
        const int s16 = threadIdx.x >> 4;
        const int i = p >> 2, j = p & 3;
        float acc = 0.f;
        const int Kk = din * 16;
        for (int kk = s16; kk < Kk; kk += 16) {
            int rrow = kk >> 4, cc = kk & 15;
            acc += W[rrow * 64 + i * 16 + cc] * W[rrow * 64 + j * 16 + cc];
        }
        red[p][s16] = acc;
        __syncthreads();
        if (threadIdx.x < 16) {
            float s = 0.f;
            for (int m = 0; m < 16; ++m) s += red[threadIdx.x][m];
            red[threadIdx.x][0] = s;
        }
        __syncthreads();
        if (threadIdx.x == 0) {
            float G[4][4], nrm[4];
            for (int a = 0; a < 4; ++a)
                for (int b = 0; b < 4; ++b) G[a][b] = red[a * 4 + b][0];
            for (int a = 0; a < 4; ++a) nrm[a] = sqrtf(G[a][a]) + 1e-12f;
            float l = 0.f;
            for (int a = 0; a < 4; ++a)
                for (int b = 0; b < 4; ++b) {
                    float gn = G[a][b] / (nrm[a] * nrm[b]);
                    float off = gn - (a == b ? 1.f : 0.f);
                    l += off * off;
                }
            total += 0.1f * l / 12.f;
        }
        __syncthreads();
    }
    if (threadIdx.x == 0) *out = total;
}

// ---------------- launcher ----------------
extern "C" void kernel_launch(void* const* d_in, const int* in_sizes, int n_in,
                              void* d_out, int out_size, void* d_ws, size_t ws_size,
                              hipStream_t stream) {
    const float* x      = (const float*)d_in[0];
    const int*   ei     = (const int*)d_in[1];
    const float* peW    = (const float*)d_in[3];
    const float* peb    = (const float*)d_in[4];

    const float* l_pW[2]   = {(const float*)d_in[5],  (const float*)d_in[17]};
    const float* l_pas[2]  = {(const float*)d_in[6],  (const float*)d_in[18]};
    const float* l_pad[2]  = {(const float*)d_in[7],  (const float*)d_in[19]};
    const float* l_posW[2] = {(const float*)d_in[8],  (const float*)d_in[20]};
    const float* l_posb[2] = {(const float*)d_in[9],  (const float*)d_in[21]};
    const float* l_dW[2]   = {(const float*)d_in[10], (const float*)d_in[22]};
    const float* l_das[2]  = {(const float*)d_in[11], (const float*)d_in[23]};
    const float* l_dad[2]  = {(const float*)d_in[12], (const float*)d_in[24]};
    const float* l_fW[2]   = {(const float*)d_in[13], (const float*)d_in[25]};
    const float* l_fb[2]   = {(const float*)d_in[14], (const float*)d_in[26]};
    const float* l_g[2]    = {(const float*)d_in[15], (const float*)d_in[27]};
    const float* l_b[2]    = {(const float*)d_in[16], (const float*)d_in[28]};
    const float* res_W  = (const float*)d_in[29];
    const float* res_b  = (const float*)d_in[30];
    const float* task_W = (const float*)d_in[31];
    const float* task_b = (const float*)d_in[32];

    float* ws = (float*)d_ws;
    float* spart   = ws + OFF_SPART;           // [BF_BLOCKS][128] stats partials
    float* pe_ws   = ws + OFF_PEWS;
    float* stats1  = ws + OFF_STAT1;
    float* wfrag   = ws + OFF_WFRAG;           // 2 x 4096 uints (fW bf16 fragments)
    float* wfrag2  = ws + OFF_WF2;             // 2 x 4096 uints (Wp/Wd bf16 fragments)
    float* pooled  = ws + OFF_POOL;            // [100][64]
    float* pooledF0= ws + OFF_POOL + 6400;     // [100][64]
    unsigned* hl   = (unsigned*)(ws + OFF_HL);    // bf16 [N][128] = [N][64] uints
    unsigned* cat_bf = (unsigned*)(ws + OFF_CAT); // bf16 [N][128] = [N][64] uints
    float* F0      = ws + OFF_F0;
    float* F1      = ws + OFF_F1;
    float* sps_p   = ws + OFF_SPSP;
    float* sps_d   = ws + OFF_SPSD;
    float2* dpd    = (float2*)(ws + OFF_DPD);
    float* stats0  = ws + OFF_STATS;
    int*   csr_off    = (int*)(ws + OFF_CSR);
    int*   sorted_src = (int*)(ws + OFF_SRT);
    float* out = (float*)d_out;

    const int NODE_BLOCKS = (N_NODES + 3) / 4;      // 25000
    const int GEMM_BLOCKS = (N_NODES + 63) / 64;    // 1563
    const int PB_BLOCKS   = N_GRAPHS * PB_PER_GRAPH; // 500

    sort_prep<<<N_GRAPHS + 4, 1024, 0, stream>>>(ei, csr_off, sorted_src,
        peW, peb, l_pW[0], l_dW[0], l_pW[1], l_dW[1], l_fW[0], l_fW[1],
        pe_ws, (uint4*)wfrag, (uint4*)wfrag2, pooled, stats0, stats1);

    // ----- layer 0 -----
    gemm_dual_mfma<true, false><<<GEMM_BLOCKS, 256, 0, stream>>>(x, (const unsigned*)wfrag2, pe_ws,
        l_pas[0], l_pad[0], l_das[0], l_dad[0], l_posW[0], l_posb[0],
        stats0, l_g[0], l_b[0], pooledF0,
        hl, sps_p, sps_d, dpd);
    gat_fused<<<NODE_BLOCKS, 256, 0, stream>>>(hl, sps_p, sps_d, dpd, csr_off, sorted_src, cat_bf);
    gemm_mfma_bf<<<BF_BLOCKS, 256, 0, stream>>>(cat_bf, (const unsigned*)wfrag,
                                                l_fb[0], F0, spart);
    reduce_stats<<<16, 128, 0, stream>>>(spart, stats0, BF_BLOCKS);

    // ----- layer 1 (BN+ELU+pool of F0 folded into the A-load) -----
    gemm_dual_mfma<false, true><<<GEMM_BLOCKS, 256, 0, stream>>>(F0, (const unsigned*)wfrag2 + 4096, pe_ws,
        l_pas[1], l_pad[1], l_das[1], l_dad[1], l_posW[1], l_posb[1],
        stats0, l_g[0], l_b[0], pooledF0,
        hl, sps_p, sps_d, dpd);
    gat_fused<<<NODE_BLOCKS, 256, 0, stream>>>(hl, sps_p, sps_d, dpd, csr_off, sorted_src, cat_bf);
    gemm_mfma_bf<<<BF_BLOCKS, 256, 0, stream>>>(cat_bf, (const unsigned*)wfrag + 4096,
                                                l_fb[1], F1, spart);
    reduce_stats<<<16, 128, 0, stream>>>(spart, stats1, BF_BLOCKS);
    pool_bn<<<PB_BLOCKS, 256, 0, stream>>>(F1, stats1, l_g[1], l_b[1], pooled);

    // ----- task head (residual folded via pooled F0) + diversity loss -----
    task_head<<<N_GRAPHS, 64, 0, stream>>>(pooled, pooledF0, res_W, res_b,
                                           task_W, task_b, out);
    div_loss<<<1, 256, 0, stream>>>(l_dW[0], l_dW[1], out + 1000);
}

// Round 18
// 419.041 us; speedup vs baseline: 1.0345x; 1.0345x over previous
//
#include <hip/hip_runtime.h>
#include <math.h>

// ---------------- static problem config ----------------
#define N_NODES   100000
#define N_GRAPHS  100
#define NPG       1000
#define N_EDGES   1600000
#define EPG       16000      // edges per graph
#define HID       16
#define HEADS     4
#define HD        64
#define OUT_DIM   10
#define BN_EPS    1e-5f
#define NEG_SLOPE 0.2f

#define LDA 68          // padded row stride for LDS tiles
#define BF_BLOCKS 782   // gemm_mfma_bf grid: 3128 waves -> 2 tiles/wave (amortized preamble)
#define PB_PER_GRAPH 5  // pool_bn blocks per graph
#define PB_NODES 200    // nodes per pool_bn block

// ---------------- workspace layout (float elements) ----------------
static const size_t OFF_SPART = 0;         // stats partials [BF_BLOCKS][128] (reused both layers)
static const size_t OFF_PEWS  = 7000000;   // 384 floats
static const size_t OFF_STAT1 = 7001000;   // 128 floats (layer-1 BN stats)
static const size_t OFF_WFRAG = 7010000;   // 2 layers x 4096 uints (fW bf16 MFMA fragments)
static const size_t OFF_WF2   = 7020000;   // 2 layers x 4096 uints (Wp/Wd bf16 MFMA B-fragments)
static const size_t OFF_POOL  = 7100000;   // pooled [100][64] ; pooledF0 at +6400
static const size_t OFF_HL    = 8000000;   // hl bf16 [N][128] = [N][64] uints
static const size_t OFF_CAT   = 20800000;  // gat_cat bf16 [N][128] = [N][64] uints
static const size_t OFF_F0    = 33600000;  // [N][64] fp32
static const size_t OFF_F1    = 40000000;  // [N][64]
static const size_t OFF_SPSP  = 46400000;  // sps plane-p [N*4]
static const size_t OFF_SPSD  = 46800000;  // sps plane-d [N*4]
static const size_t OFF_DPD   = 47200000;  // dpd float2 [N][4]  (d_p_adj, d_d)
static const size_t OFF_STATS = 48000000;  // 128 floats (layer-0 BN stats)
static const size_t OFF_CSR   = 48000128;  // ints
static const size_t OFF_SRT   = 48100144;  // ints

// ---------------- bf16 helpers (RNE pack, exact unpack) ----------------
__device__ inline unsigned bf_pack(float x, float y) {
    unsigned ux = __float_as_uint(x);
    unsigned uy = __float_as_uint(y);
    ux = (ux + 0x7FFFu + ((ux >> 16) & 1u)) >> 16;
    uy = ((uy + 0x7FFFu + ((uy >> 16) & 1u)) >> 16) << 16;
    return ux | uy;
}
__device__ inline float bf_lo(unsigned u) { return __uint_as_float(u << 16); }
__device__ inline float bf_hi(unsigned u) { return __uint_as_float(u & 0xFFFF0000u); }

// MFMA fragment types (gfx950: 16x16x32 bf16 -> 8 bf16 in, 4 f32 acc)
typedef __attribute__((ext_vector_type(8))) short bf16x8;
typedef __attribute__((ext_vector_type(4))) float f32x4;

__device__ inline bf16x8 frag_from(unsigned a, unsigned b, unsigned c, unsigned d) {
    uint4 u{a, b, c, d};
    return *reinterpret_cast<bf16x8*>(&u);
}

// ---------------- per-graph counting sort of edges by dst + merged prep ----------------
// Blocks 0..99: per-graph counting sort. Blocks 100..103: prep work (PE collapse,
// W fragments, zero-init) running concurrently -- saves one launch + serialization.
__global__ __launch_bounds__(1024) void sort_prep(const int* __restrict__ ei,
                                                  int* __restrict__ csr_off,
                                                  int* __restrict__ sorted_src,
                                                  const float* __restrict__ peW, const float* __restrict__ peb,
                                                  const float* __restrict__ pW0, const float* __restrict__ dW0,
                                                  const float* __restrict__ pW1, const float* __restrict__ dW1,
                                                  const float* __restrict__ fW0, const float* __restrict__ fW1,
                                                  float* __restrict__ pe,
                                                  uint4* __restrict__ wfA,
                                                  uint4* __restrict__ wfD,
                                                  float* __restrict__ pool2,
                                                  float* __restrict__ stats0,
                                                  float* __restrict__ stats1) {
    const int g = blockIdx.x;
    const int t = threadIdx.x;
    if (g >= N_GRAPHS) {
        const int b = g - N_GRAPHS;
        if (b == 0) {
            if (t < 128) {
                int r = t >> 6, c = t & 63;
                float sp = 0.f, sd = 0.f;
                for (int m = 0; m < 16; ++m) {
                    sp += peW[r * 16 + m] * pW0[(64 + m) * 64 + c];
                    sd += peW[r * 16 + m] * dW0[(64 + m) * 64 + c];
                }
                pe[r * 64 + c] = sp;
                pe[192 + r * 64 + c] = sd;
            } else if (t < 192) {
                int c = t & 63;
                float sp = 0.f, sd = 0.f;
                for (int m = 0; m < 16; ++m) {
                    sp += peb[m] * pW0[(64 + m) * 64 + c];
                    sd += peb[m] * dW0[(64 + m) * 64 + c];
                }
                pe[128 + c] = sp;
                pe[320 + c] = sd;
            }
        } else if (b == 1) {
            if (t < 256)
            for (int i = t; i < 2 * 4 * 4 * 64; i += 256) {
                const int lane  = i & 63;
                const int ct    = (i >> 6) & 3;
                const int kk    = (i >> 8) & 3;
                const int layer = i >> 10;
                const float* W = layer ? fW1 : fW0;
                const int col = ct * 16 + (lane & 15);
                const int kb  = kk * 32 + (lane >> 4) * 8;
                uint4 u;
                u.x = bf_pack(W[(kb + 0) * 64 + col], W[(kb + 1) * 64 + col]);
                u.y = bf_pack(W[(kb + 2) * 64 + col], W[(kb + 3) * 64 + col]);
                u.z = bf_pack(W[(kb + 4) * 64 + col], W[(kb + 5) * 64 + col]);
                u.w = bf_pack(W[(kb + 6) * 64 + col], W[(kb + 7) * 64 + col]);
                wfA[i] = u;
            }
        } else if (b == 2) {
            if (t < 256)
            for (int i = t; i < 2048; i += 256) {
                const int lane  = i & 63;
                const int ct    = (i >> 6) & 3;
                const int kk    = (i >> 8) & 1;
                const int mat   = (i >> 9) & 1;
                const int layer = i >> 10;
                const float* W = layer ? (mat ? dW1 : pW1) : (mat ? dW0 : pW0);
                const int col = ct * 16 + (lane & 15);
                const int kb  = kk * 32 + (lane >> 4) * 8;
                uint4 u;
                u.x = bf_pack(W[(kb + 0) * 64 + col], W[(kb + 1) * 64 + col]);
                u.y = bf_pack(W[(kb + 2) * 64 + col], W[(kb + 3) * 64 + col]);
                u.z = bf_pack(W[(kb + 4) * 64 + col], W[(kb + 5) * 64 + col]);
                u.w = bf_pack(W[(kb + 6) * 64 + col], W[(kb + 7) * 64 + col]);
                wfD[i] = u;
            }
        } else {
            for (int i = t; i < 2 * N_GRAPHS * 64; i += 1024) pool2[i] = 0.f;
            if (t < 128) { stats0[t] = 0.f; stats1[t] = 0.f; }
        }
        return;
    }

    __shared__ int hist[1024];
    __shared__ int scan[1024];
    const int* src = ei;
    const int* dst = ei + N_EDGES;
    const int e0 = g * EPG;
    const int nbase = g * NPG;

    hist[t] = 0;
    __syncthreads();
    for (int i = t; i < EPG; i += 1024) {
        int d = dst[e0 + i] - nbase;
        atomicAdd(&hist[d], 1);
    }
    __syncthreads();
    scan[t] = hist[t];
    __syncthreads();
    for (int off = 1; off < 1024; off <<= 1) {
        int v = (t >= off) ? scan[t - off] : 0;
        __syncthreads();
        scan[t] += v;
        __syncthreads();
    }
    int excl = scan[t] - hist[t];
    if (t < NPG) csr_off[nbase + t] = e0 + excl;
    if (g == 0 && t == 0) csr_off[N_NODES] = N_EDGES;
    __syncthreads();
    hist[t] = excl;
    __syncthreads();
    for (int i = t; i < EPG; i += 1024) {
        int s = src[e0 + i];
        int d = dst[e0 + i] - nbase;
        int slot = atomicAdd(&hist[d], 1);
        sorted_src[e0 + slot] = s;
    }
}

// ---------------- stats partial reduction: spart[nb][128] -> stats[128] ----------------
__global__ __launch_bounds__(128) void reduce_stats(const float* __restrict__ part,
                                                    float* __restrict__ stats, int nb) {
    const int c = threadIdx.x;           // 0..127
    const int per = (nb + gridDim.x - 1) / gridDim.x;
    const int b0 = blockIdx.x * per;
    int b1 = b0 + per; if (b1 > nb) b1 = nb;
    float s = 0.f;
    for (int b = b0; b < b1; ++b) s += part[(size_t)b * 128 + c];
    atomicAdd(&stats[c], s);
}

// ---------------- MFMA dual GEMM (K=64) + fused attention-logit epilogue ----------------
// A (f32) split hi/lo bf16 in registers; W bf16. 32 MFMA per 16-node wave-tile;
// acc -> LDS; one barrier; epilogue folds positional attention into sps/dpd.
// BN=true (layer 1): A-load applies BN(scale/shift from stats)+ELU on the fly and
// accumulates per-graph pooling of the transformed values.
// NOTE (R15): 2-tiles/block + hoisted preamble regressed (VGPR 84->108); 1 tile/block.
// NOTE (R17): LDS-halved plane-sequential variant improved this kernel but total
// regressed on that container; per pre-commitment the full-LDS variant is final.
template <bool PE, bool BN>
__global__ __launch_bounds__(256) void gemm_dual_mfma(const float* __restrict__ A,
                                                      const unsigned* __restrict__ wf2,
                                                      const float* __restrict__ pe,
                                                      const float* __restrict__ pas,
                                                      const float* __restrict__ pad_,
                                                      const float* __restrict__ das,
                                                      const float* __restrict__ dad,
                                                      const float* __restrict__ posW,
                                                      const float* __restrict__ posb,
                                                      const float* __restrict__ stats,
                                                      const float* __restrict__ gamma,
                                                      const float* __restrict__ beta,
                                                      float* __restrict__ poolF,
                                                      unsigned* __restrict__ hl,
                                                      float* __restrict__ sps_p,
                                                      float* __restrict__ sps_d,
                                                      float2* __restrict__ dpd) {
    __shared__ float sD[4 * 2 * 16 * LDA];   // [wave][plane][row][LDA] = 34816 B
    const int t = threadIdx.x;
    const int w = t >> 6, lane = t & 63;
    const int cidx = lane & 15, khi = lane >> 4;
    const int node0 = blockIdx.x * 64;

    // preload W fragments [mat][kk][ct]
    bf16x8 wf[2][2][4];
#pragma unroll
    for (int mat = 0; mat < 2; ++mat)
#pragma unroll
        for (int kk = 0; kk < 2; ++kk)
#pragma unroll
            for (int ct = 0; ct < 4; ++ct)
                wf[mat][kk][ct] = *reinterpret_cast<const bf16x8*>(
                    wf2 + (size_t)((((mat * 2 + kk) * 4 + ct) * 64) + lane) * 4);

    // load A row (BN path: normalize+ELU+pool), build hi/lo fragments
    const int node0w = node0 + w * 16;
    int gn = node0w + cidx; if (gn > N_NODES - 1) gn = N_NODES - 1;
    const float* ar = A + (size_t)gn * 64;
    bf16x8 ah[2], al[2];
#pragma unroll
    for (int kk = 0; kk < 2; ++kk) {
        const int k0 = kk * 32 + khi * 8;
        float4 f0 = *reinterpret_cast<const float4*>(ar + k0);
        float4 f1 = *reinterpret_cast<const float4*>(ar + k0 + 4);
        if (BN) {
            const float invN = 1.0f / (float)N_NODES;
            float4 sa = *reinterpret_cast<const float4*>(&stats[k0]);
            float4 sb = *reinterpret_cast<const float4*>(&stats[k0 + 4]);
            float4 qa = *reinterpret_cast<const float4*>(&stats[64 + k0]);
            float4 qb = *reinterpret_cast<const float4*>(&stats[64 + k0 + 4]);
            float4 ga = *reinterpret_cast<const float4*>(&gamma[k0]);
            float4 gb = *reinterpret_cast<const float4*>(&gamma[k0 + 4]);
            float4 ba = *reinterpret_cast<const float4*>(&beta[k0]);
            float4 bb = *reinterpret_cast<const float4*>(&beta[k0 + 4]);
            float sc[8], sh[8];
            float ss[8] = {sa.x, sa.y, sa.z, sa.w, sb.x, sb.y, sb.z, sb.w};
            float qq[8] = {qa.x, qa.y, qa.z, qa.w, qb.x, qb.y, qb.z, qb.w};
            float gg[8] = {ga.x, ga.y, ga.z, ga.w, gb.x, gb.y, gb.z, gb.w};
            float bt[8] = {ba.x, ba.y, ba.z, ba.w, bb.x, bb.y, bb.z, bb.w};
#pragma unroll
            for (int i = 0; i < 8; ++i) {
                float mu = ss[i] * invN;
                float var = qq[i] * invN - mu * mu;
                float iv = rsqrtf(var + BN_EPS);
                sc[i] = iv * gg[i];
                sh[i] = bt[i] - mu * sc[i];
            }
            auto ap = [&](float v, int i) {
                float r = fmaf(v, sc[i], sh[i]);
                return r > 0.f ? r : (__expf(r) - 1.f);
            };
            f0.x = ap(f0.x, 0); f0.y = ap(f0.y, 1); f0.z = ap(f0.z, 2); f0.w = ap(f0.w, 3);
            f1.x = ap(f1.x, 4); f1.y = ap(f1.y, 5); f1.z = ap(f1.z, 6); f1.w = ap(f1.w, 7);
            // per-graph pooling of transformed values (Σ over nodes)
            if (node0w < N_NODES) {
                const int node_l = node0w + cidx;
                const bool okn = node_l < N_NODES;
                const int gl = node_l / NPG;
                const int g0 = node0w / NPG;
                int lastn = node0w + 15; if (lastn > N_NODES - 1) lastn = N_NODES - 1;
                const int g1 = lastn / NPG;
                float p8[8] = {f0.x, f0.y, f0.z, f0.w, f1.x, f1.y, f1.z, f1.w};
                {
                    const bool m = okn && (gl == g0);
#pragma unroll
                    for (int i = 0; i < 8; ++i) {
                        float tv = m ? p8[i] : 0.f;
                        tv += __shfl_xor(tv, 1); tv += __shfl_xor(tv, 2);
                        tv += __shfl_xor(tv, 4); tv += __shfl_xor(tv, 8);
                        if (cidx == 0) atomicAdd(&poolF[g0 * 64 + k0 + i], tv);
                    }
                }
                if (g1 != g0) {
                    const bool m = okn && (gl == g1);
#pragma unroll
                    for (int i = 0; i < 8; ++i) {
                        float tv = m ? p8[i] : 0.f;
                        tv += __shfl_xor(tv, 1); tv += __shfl_xor(tv, 2);
                        tv += __shfl_xor(tv, 4); tv += __shfl_xor(tv, 8);
                        if (cidx == 0) atomicAdd(&poolF[g1 * 64 + k0 + i], tv);
                    }
                }
            }
        }
        unsigned h0 = bf_pack(f0.x, f0.y), h1 = bf_pack(f0.z, f0.w);
        unsigned h2 = bf_pack(f1.x, f1.y), h3 = bf_pack(f1.z, f1.w);
        unsigned l0 = bf_pack(f0.x - bf_lo(h0), f0.y - bf_hi(h0));
        unsigned l1 = bf_pack(f0.z - bf_lo(h1), f0.w - bf_hi(h1));
        unsigned l2 = bf_pack(f1.x - bf_lo(h2), f1.y - bf_hi(h2));
        unsigned l3 = bf_pack(f1.z - bf_lo(h3), f1.w - bf_hi(h3));
        ah[kk] = frag_from(h0, h1, h2, h3);
        al[kk] = frag_from(l0, l1, l2, l3);
    }

    f32x4 ap4[4], ad4[4];
#pragma unroll
    for (int ct = 0; ct < 4; ++ct) { ap4[ct] = 0.f; ad4[ct] = 0.f; }
#pragma unroll
    for (int ct = 0; ct < 4; ++ct) {
        ap4[ct] = __builtin_amdgcn_mfma_f32_16x16x32_bf16(ah[0], wf[0][0][ct], ap4[ct], 0, 0, 0);
        ap4[ct] = __builtin_amdgcn_mfma_f32_16x16x32_bf16(ah[1], wf[0][1][ct], ap4[ct], 0, 0, 0);
        ap4[ct] = __builtin_amdgcn_mfma_f32_16x16x32_bf16(al[0], wf[0][0][ct], ap4[ct], 0, 0, 0);
        ap4[ct] = __builtin_amdgcn_mfma_f32_16x16x32_bf16(al[1], wf[0][1][ct], ap4[ct], 0, 0, 0);
        ad4[ct] = __builtin_amdgcn_mfma_f32_16x16x32_bf16(ah[0], wf[1][0][ct], ad4[ct], 0, 0, 0);
        ad4[ct] = __builtin_amdgcn_mfma_f32_16x16x32_bf16(ah[1], wf[1][1][ct], ad4[ct], 0, 0, 0);
        ad4[ct] = __builtin_amdgcn_mfma_f32_16x16x32_bf16(al[0], wf[1][0][ct], ad4[ct], 0, 0, 0);
        ad4[ct] = __builtin_amdgcn_mfma_f32_16x16x32_bf16(al[1], wf[1][1][ct], ad4[ct], 0, 0, 0);
    }

    // D layout: lane holds D[khi*4+q][ct*16+cidx]  -> scatter to LDS
    {
        float* base = sD + w * (2 * 16 * LDA);
#pragma unroll
        for (int ct = 0; ct < 4; ++ct)
#pragma unroll
            for (int q = 0; q < 4; ++q) {
                base[(khi * 4 + q) * LDA + ct * 16 + cidx]                 = ap4[ct][q];
                base[16 * LDA + (khi * 4 + q) * LDA + ct * 16 + cidx]      = ad4[ct][q];
            }
    }
    __syncthreads();

    // ---- epilogue, reading LDS ----
    const int tx = t & 15, ty = t >> 4;
    const int c4 = tx * 4;
    float4 accp[4], accd[4];
#pragma unroll
    for (int j = 0; j < 4; ++j) {
        const int n = ty * 4 + j;
        const float* bp = sD + (n >> 4) * (2 * 16 * LDA) + (n & 15) * LDA;
        accp[j] = *reinterpret_cast<const float4*>(bp + c4);
        accd[j] = *reinterpret_cast<const float4*>(bp + 16 * LDA + c4);
    }

    if (PE) {
        float4 pp0 = *reinterpret_cast<const float4*>(&pe[c4]);
        float4 pp1 = *reinterpret_cast<const float4*>(&pe[64 + c4]);
        float4 ppb = *reinterpret_cast<const float4*>(&pe[128 + c4]);
        float4 pd0 = *reinterpret_cast<const float4*>(&pe[192 + c4]);
        float4 pd1 = *reinterpret_cast<const float4*>(&pe[256 + c4]);
        float4 pdb = *reinterpret_cast<const float4*>(&pe[320 + c4]);
#pragma unroll
        for (int j = 0; j < 4; ++j) {
            int node = node0 + ty * 4 + j;
            int r = node % NPG;
            float px = (float)(r >> 5) * (1.0f / 31.0f);
            float py = (float)(r & 31) * (1.0f / 31.0f);
            accp[j].x += px * pp0.x + py * pp1.x + ppb.x;
            accp[j].y += px * pp0.y + py * pp1.y + ppb.y;
            accp[j].z += px * pp0.z + py * pp1.z + ppb.z;
            accp[j].w += px * pp0.w + py * pp1.w + ppb.w;
            accd[j].x += px * pd0.x + py * pd1.x + pdb.x;
            accd[j].y += px * pd0.y + py * pd1.y + pdb.y;
            accd[j].z += px * pd0.z + py * pd1.z + pdb.z;
            accd[j].w += px * pd0.w + py * pd1.w + pdb.w;
        }
    }

    float4 pasv = *reinterpret_cast<const float4*>(&pas[c4]);
    float4 padv = *reinterpret_cast<const float4*>(&pad_[c4]);
    float4 dasv = *reinterpret_cast<const float4*>(&das[c4]);
    float4 dadv = *reinterpret_cast<const float4*>(&dad[c4]);
    const int h = tx >> 2;
    const float pw0 = posW[h], pw1 = posW[4 + h], pb = posb[h];
    const int cu = tx * 2;   // uint index within 64-uint row
#pragma unroll
    for (int j = 0; j < 4; ++j) {
        const int node = node0 + ty * 4 + j;
        float vps = accp[j].x * pasv.x + accp[j].y * pasv.y + accp[j].z * pasv.z + accp[j].w * pasv.w;
        float vpd = accp[j].x * padv.x + accp[j].y * padv.y + accp[j].z * padv.z + accp[j].w * padv.w;
        float vds = accd[j].x * dasv.x + accd[j].y * dasv.y + accd[j].z * dasv.z + accd[j].w * dasv.w;
        float vdd = accd[j].x * dadv.x + accd[j].y * dadv.y + accd[j].z * dadv.z + accd[j].w * dadv.w;
        vps += __shfl_xor(vps, 1); vps += __shfl_xor(vps, 2);
        vpd += __shfl_xor(vpd, 1); vpd += __shfl_xor(vpd, 2);
        vds += __shfl_xor(vds, 1); vds += __shfl_xor(vds, 2);
        vdd += __shfl_xor(vdd, 1); vdd += __shfl_xor(vdd, 2);
        if (node < N_NODES) {
            uint2 up, ud;
            up.x = bf_pack(accp[j].x, accp[j].y); up.y = bf_pack(accp[j].z, accp[j].w);
            ud.x = bf_pack(accd[j].x, accd[j].y); ud.y = bf_pack(accd[j].z, accd[j].w);
            *reinterpret_cast<uint2*>(&hl[(size_t)node * 64 + cu])      = up;
            *reinterpret_cast<uint2*>(&hl[(size_t)node * 64 + 32 + cu]) = ud;
            if ((tx & 3) == 0) {
                const int r = node % NPG;
                const float pxn = (float)(r >> 5) * (1.0f / 31.0f);
                const float pyn = (float)(r & 31) * (1.0f / 31.0f);
                const float posdot = pxn * pw0 + pyn * pw1;
                sps_p[node * 4 + h] = vps - posdot;
                sps_d[node * 4 + h] = vds;
                dpd[node * 4 + h] = float2{vpd + posdot + pb, vdd};
            }
        }
    }
}

// ---------------- MFMA GEMM: out = bf16A[N,128] @ Wbf[128,64] + b, + BN stat partials ----------------
__global__ __launch_bounds__(256) void gemm_mfma_bf(const unsigned* __restrict__ A,
                                                    const unsigned* __restrict__ wfrag,
                                                    const float* __restrict__ bias,
                                                    float* __restrict__ out,
                                                    float* __restrict__ spart) {
    __shared__ float red[512];
    const int t = threadIdx.x;
    const int lane = t & 63;
    const int cidx = lane & 15;   // A-frag row within tile; D col within col-tile
    const int khi  = lane >> 4;   // k-group for A/B frags; D row-group

    bf16x8 wf[4][4];
#pragma unroll
    for (int kk = 0; kk < 4; ++kk)
#pragma unroll
        for (int ct = 0; ct < 4; ++ct)
            wf[kk][ct] = *reinterpret_cast<const bf16x8*>(wfrag + (size_t)((kk * 4 + ct) * 64 + lane) * 4);

    float bias_r[4];
#pragma unroll
    for (int ct = 0; ct < 4; ++ct) bias_r[ct] = bias[ct * 16 + cidx];

    float ls[4] = {0.f, 0.f, 0.f, 0.f};
    float lq[4] = {0.f, 0.f, 0.f, 0.f};

    const int NW  = gridDim.x << 2;
    const int wid = (blockIdx.x << 2) + (t >> 6);
    for (int tile = wid; tile < N_NODES / 16; tile += NW) {
        const int node0 = tile << 4;
        const unsigned* arow = A + (size_t)(node0 + cidx) * 64 + khi * 4;
        bf16x8 a0 = *reinterpret_cast<const bf16x8*>(arow);
        bf16x8 a1 = *reinterpret_cast<const bf16x8*>(arow + 16);
        bf16x8 a2 = *reinterpret_cast<const bf16x8*>(arow + 32);
        bf16x8 a3 = *reinterpret_cast<const bf16x8*>(arow + 48);

        f32x4 acc[4];
#pragma unroll
        for (int ct = 0; ct < 4; ++ct) acc[ct] = 0.f;
#pragma unroll
        for (int ct = 0; ct < 4; ++ct) {
            acc[ct] = __builtin_amdgcn_mfma_f32_16x16x32_bf16(a0, wf[0][ct], acc[ct], 0, 0, 0);
            acc[ct] = __builtin_amdgcn_mfma_f32_16x16x32_bf16(a1, wf[1][ct], acc[ct], 0, 0, 0);
            acc[ct] = __builtin_amdgcn_mfma_f32_16x16x32_bf16(a2, wf[2][ct], acc[ct], 0, 0, 0);
            acc[ct] = __builtin_amdgcn_mfma_f32_16x16x32_bf16(a3, wf[3][ct], acc[ct], 0, 0, 0);
        }

        const int nbase = node0 + (khi << 2);
#pragma unroll
        for (int ct = 0; ct < 4; ++ct) {
#pragma unroll
            for (int q = 0; q < 4; ++q) {
                float v = acc[ct][q] + bias_r[ct];
                out[(size_t)(nbase + q) * 64 + ct * 16 + cidx] = v;
                ls[ct] += v;
                lq[ct] = fmaf(v, v, lq[ct]);
            }
        }
    }

#pragma unroll
    for (int ct = 0; ct < 4; ++ct) {
        ls[ct] += __shfl_xor(ls[ct], 16); ls[ct] += __shfl_xor(ls[ct], 32);
        lq[ct] += __shfl_xor(lq[ct], 16); lq[ct] += __shfl_xor(lq[ct], 32);
    }
    if (lane < 16) {
        const int w = t >> 6;
#pragma unroll
        for (int ct = 0; ct < 4; ++ct) {
            red[w * 64 + ct * 16 + lane]       = ls[ct];
            red[256 + w * 64 + ct * 16 + lane] = lq[ct];
        }
    }
    __syncthreads();
    if (t < 64) {
        float s  = red[t] + red[64 + t] + red[128 + t] + red[192 + t];
        float sq = red[256 + t] + red[320 + t] + red[384 + t] + red[448 + t];
        spart[(size_t)blockIdx.x * 128 + t]      = s;
        spart[(size_t)blockIdx.x * 128 + 64 + t] = sq;
    }
}

// ---------------- fused dual-GAT, cooperative weights, batched gathers ----------------
// Remainder chunk uses the SAME straight-line 8-wide batch as the main loop:
// phase-1 masks w=0 for lanes j1>=nj and the gather index is clamped to a valid
// edge, so shuffled weights for jj>=nj are exactly 0.0 and the extra FMAs are
// bit-exact no-ops.
__global__ __launch_bounds__(256) void gat_fused(const unsigned* __restrict__ hl,
                                                 const float* __restrict__ sps_p,
                                                 const float* __restrict__ sps_d,
                                                 const float2* __restrict__ dpd,
                                                 const int* __restrict__ csr_off,
                                                 const int* __restrict__ sorted_src,
                                                 unsigned* __restrict__ gat_cat) {
    const int b = blockIdx.x;
    const int logical = (b & 7) * 3125 + (b >> 3);   // XCD-aware swizzle
    const int v = logical * 4 + (threadIdx.x >> 6);
    if (v >= N_NODES) return;
    const int lane = threadIdx.x & 63;
    const int j1 = lane >> 3;
    const int p1 = (lane >> 2) & 1;
    const int h1 = lane & 3;
    const int phneed = ((lane >> 5) << 2) | ((lane & 31) >> 3);

    const float* __restrict__ spl = p1 ? sps_d : sps_p;
    const float2 dv1 = dpd[(size_t)v * 4 + h1];
    const float dval1 = p1 ? dv1.y : dv1.x;

    const int beg = __builtin_amdgcn_readfirstlane(csr_off[v]);
    const int end = __builtin_amdgcn_readfirstlane(csr_off[v + 1]);

    float2 acc = {0.f, 0.f};
    float wpart = 0.f;
    int e = beg;
    const int nfull = (end - beg) >> 3;

    int sA = 0, sB = 0;
    float svA = 0.f, svB = 0.f;
    if (nfull >= 1) { sA = sorted_src[e + j1]; svA = spl[(size_t)sA * 4 + h1]; }
    if (nfull >= 2) { sB = sorted_src[e + 8 + j1]; }

    for (int k = 0; k < nfull; ++k, e += 8) {
        int sC = 0;
        if (k + 2 < nfull) sC = sorted_src[e + 16 + j1];
        if (k + 1 < nfull) svB = spl[(size_t)sB * 4 + h1];
        float w = svA + dval1;
        w = fmaxf(w, NEG_SLOPE * w);
        w = __expf(w);
        wpart += w;
        // broadcast src rows + class weights
        int sj0 = __builtin_amdgcn_readlane(sA, 0);
        int sj1 = __builtin_amdgcn_readlane(sA, 8);
        int sj2 = __builtin_amdgcn_readlane(sA, 16);
        int sj3 = __builtin_amdgcn_readlane(sA, 24);
        int sj4 = __builtin_amdgcn_readlane(sA, 32);
        int sj5 = __builtin_amdgcn_readlane(sA, 40);
        int sj6 = __builtin_amdgcn_readlane(sA, 48);
        int sj7 = __builtin_amdgcn_readlane(sA, 56);
        float wj0 = __shfl(w, 0 + phneed);
        float wj1 = __shfl(w, 8 + phneed);
        float wj2 = __shfl(w, 16 + phneed);
        float wj3 = __shfl(w, 24 + phneed);
        float wj4 = __shfl(w, 32 + phneed);
        float wj5 = __shfl(w, 40 + phneed);
        float wj6 = __shfl(w, 48 + phneed);
        float wj7 = __shfl(w, 56 + phneed);
        // issue all gathers up front
        unsigned u0 = hl[((size_t)sj0 << 6) + lane];
        unsigned u1 = hl[((size_t)sj1 << 6) + lane];
        unsigned u2 = hl[((size_t)sj2 << 6) + lane];
        unsigned u3 = hl[((size_t)sj3 << 6) + lane];
        unsigned u4 = hl[((size_t)sj4 << 6) + lane];
        unsigned u5 = hl[((size_t)sj5 << 6) + lane];
        unsigned u6 = hl[((size_t)sj6 << 6) + lane];
        unsigned u7 = hl[((size_t)sj7 << 6) + lane];
        acc.x = fmaf(wj0, bf_lo(u0), acc.x); acc.y = fmaf(wj0, bf_hi(u0), acc.y);
        acc.x = fmaf(wj1, bf_lo(u1), acc.x); acc.y = fmaf(wj1, bf_hi(u1), acc.y);
        acc.x = fmaf(wj2, bf_lo(u2), acc.x); acc.y = fmaf(wj2, bf_hi(u2), acc.y);
        acc.x = fmaf(wj3, bf_lo(u3), acc.x); acc.y = fmaf(wj3, bf_hi(u3), acc.y);
        acc.x = fmaf(wj4, bf_lo(u4), acc.x); acc.y = fmaf(wj4, bf_hi(u4), acc.y);
        acc.x = fmaf(wj5, bf_lo(u5), acc.x); acc.y = fmaf(wj5, bf_hi(u5), acc.y);
        acc.x = fmaf(wj6, bf_lo(u6), acc.x); acc.y = fmaf(wj6, bf_hi(u6), acc.y);
        acc.x = fmaf(wj7, bf_lo(u7), acc.x); acc.y = fmaf(wj7, bf_hi(u7), acc.y);
        sA = sB; sB = sC; svA = svB;
    }

    if (e < end) {
        const int nj = end - e;
        int ee = e + j1; if (ee >= end) ee = end - 1;
        int s = sorted_src[ee];
        float sval = spl[(size_t)s * 4 + h1];
        float w = sval + dval1;
        w = fmaxf(w, NEG_SLOPE * w);
        w = __expf(w);
        if (j1 >= nj) w = 0.f;
        wpart += w;
        // full 8-wide batch (weights for jj>=nj are exactly 0; clamped gathers valid)
        int sj0 = __builtin_amdgcn_readlane(s, 0);
        int sj1 = __builtin_amdgcn_readlane(s, 8);
        int sj2 = __builtin_amdgcn_readlane(s, 16);
        int sj3 = __builtin_amdgcn_readlane(s, 24);
        int sj4 = __builtin_amdgcn_readlane(s, 32);
        int sj5 = __builtin_amdgcn_readlane(s, 40);
        int sj6 = __builtin_amdgcn_readlane(s, 48);
        int sj7 = __builtin_amdgcn_readlane(s, 56);
        float wj0 = __shfl(w, 0 + phneed);
        float wj1 = __shfl(w, 8 + phneed);
        float wj2 = __shfl(w, 16 + phneed);
        float wj3 = __shfl(w, 24 + phneed);
        float wj4 = __shfl(w, 32 + phneed);
        float wj5 = __shfl(w, 40 + phneed);
        float wj6 = __shfl(w, 48 + phneed);
        float wj7 = __shfl(w, 56 + phneed);
        unsigned u0 = hl[((size_t)sj0 << 6) + lane];
        unsigned u1 = hl[((size_t)sj1 << 6) + lane];
        unsigned u2 = hl[((size_t)sj2 << 6) + lane];
        unsigned u3 = hl[((size_t)sj3 << 6) + lane];
        unsigned u4 = hl[((size_t)sj4 << 6) + lane];
        unsigned u5 = hl[((size_t)sj5 << 6) + lane];
        unsigned u6 = hl[((size_t)sj6 << 6) + lane];
        unsigned u7 = hl[((size_t)sj7 << 6) + lane];
        acc.x = fmaf(wj0, bf_lo(u0), acc.x); acc.y = fmaf(wj0, bf_hi(u0), acc.y);
        acc.x = fmaf(wj1, bf_lo(u1), acc.x); acc.y = fmaf(wj1, bf_hi(u1), acc.y);
        acc.x = fmaf(wj2, bf_lo(u2), acc.x); acc.y = fmaf(wj2, bf_hi(u2), acc.y);
        acc.x = fmaf(wj3, bf_lo(u3), acc.x); acc.y = fmaf(wj3, bf_hi(u3), acc.y);
        acc.x = fmaf(wj4, bf_lo(u4), acc.x); acc.y = fmaf(wj4, bf_hi(u4), acc.y);
        acc.x = fmaf(wj5, bf_lo(u5), acc.x); acc.y = fmaf(wj5, bf_hi(u5), acc.y);
        acc.x = fmaf(wj6, bf_lo(u6), acc.x); acc.y = fmaf(wj6, bf_hi(u6), acc.y);
        acc.x = fmaf(wj7, bf_lo(u7), acc.x); acc.y = fmaf(wj7, bf_hi(u7), acc.y);
    }
    wpart += __shfl_xor(wpart, 8);
    wpart += __shfl_xor(wpart, 16);
    wpart += __shfl_xor(wpart, 32);
    const float wsum = __shfl(wpart, phneed);
    const float inv = 1.0f / (wsum + 1e-16f);
    gat_cat[(size_t)v * 64 + lane] = bf_pack(acc.x * inv, acc.y * inv);
}

// ---------------- BN + ELU + graph pooling, chain-free ----------------
__global__ __launch_bounds__(256) void pool_bn(const float* __restrict__ F, const float* __restrict__ stats,
                                               const float* __restrict__ gamma, const float* __restrict__ beta,
                                               float* __restrict__ pooled) {
    __shared__ float red[256];
    const int b = blockIdx.x;
    const int g = b / PB_PER_GRAPH;
    const int n0 = g * NPG + (b % PB_PER_GRAPH) * PB_NODES;
    const int t = threadIdx.x;
    const int c = t & 63, rg = t >> 6;
    const float mu = stats[c] * (1.0f / (float)N_NODES);
    const float var = stats[64 + c] * (1.0f / (float)N_NODES) - mu * mu;
    const float iv = rsqrtf(var + BN_EPS);
    const float sc = iv * gamma[c];
    const float sh = beta[c] - mu * sc;
    float s = 0.f;
    for (int i = rg; i < PB_NODES; i += 4) {
        float v = fmaf(F[(size_t)(n0 + i) * 64 + c], sc, sh);
        v = (v > 0.f) ? v : expm1f(v);
        s += v;
    }
    red[t] = s;
    __syncthreads();
    if (t < 64)
        atomicAdd(&pooled[g * 64 + c], red[c] + red[64 + c] + red[128 + c] + red[192 + c]);
}

// ---------------- task head: one wave per graph, residual folded in via pooled F0 ----------------
__global__ __launch_bounds__(64) void task_head(const float* __restrict__ pooled,
                                                const float* __restrict__ pooledF0,
                                                const float* __restrict__ resW,
                                                const float* __restrict__ resb,
                                                const float* __restrict__ taskW,
                                                const float* __restrict__ taskb,
                                                float* __restrict__ out) {
    const int g = blockIdx.x;
    const int c = threadIdx.x;
    float rc = 0.f;
    const float* pf = pooledF0 + g * 64;
    for (int k = 0; k < 64; ++k)
        rc = fmaf(pf[k], resW[k * 64 + c], rc);
    float p = (pooled[g * 64 + c] + rc) * (1.0f / (float)NPG) + resb[c];
#pragma unroll
    for (int o = 0; o < OUT_DIM; ++o) {
        float partial = p * taskW[c * OUT_DIM + o];
#pragma unroll
        for (int m = 1; m < 64; m <<= 1) partial += __shfl_xor(partial, m);
        if (c == 0) out[g * OUT_DIM + o] = partial + taskb[o];
    }
}

// ---------------- head-diversity loss for both layers ----------------
__global__ __launch_bounds__(256) void div_loss(const float* __restrict__ dW0,
                                                const float* __restrict__ dW1,
                                                float* __restrict__ out) {
    __shared__ float red[16][16];
    float total = 0.f;
    for (int layer = 0; layer < 2; ++layer) {
        const float* W = layer ? dW1 : dW0;
        const int din = layer ? 64 : 80;
        const int p = threadIdx.x & 15;
        const int s16 = threadIdx.x >> 4;
        const int i = p >> 2, j = p & 3;
        float acc = 0.f;
        const int Kk = din * 16;
        for (int kk = s16; kk < Kk; kk += 16) {
            int rrow = kk >> 4, cc = kk & 15;
            acc += W[rrow * 64 + i * 16 + cc] * W[rrow * 64 + j * 16 + cc];
        }
        red[p][s16] = acc;
        __syncthreads();
        if (threadIdx.x < 16) {
            float s = 0.f;
            for (int m = 0; m < 16; ++m) s += red[threadIdx.x][m];
            red[threadIdx.x][0] = s;
        }
        __syncthreads();
        if (threadIdx.x == 0) {
            float G[4][4], nrm[4];
            for (int a = 0; a < 4; ++a)
                for (int b = 0; b < 4; ++b) G[a][b] = red[a * 4 + b][0];
            for (int a = 0; a < 4; ++a) nrm[a] = sqrtf(G[a][a]) + 1e-12f;
            float l = 0.f;
            for (int a = 0; a < 4; ++a)
                for (int b = 0; b < 4; ++b) {
                    float gn = G[a][b] / (nrm[a] * nrm[b]);
                    float off = gn - (a == b ? 1.f : 0.f);
                    l += off * off;
                }
            total += 0.1f * l / 12.f;
        }
        __syncthreads();
    }
    if (threadIdx.x == 0) *out = total;
}

// ---------------- launcher ----------------
extern "C" void kernel_launch(void* const* d_in, const int* in_sizes, int n_in,
                              void* d_out, int out_size, void* d_ws, size_t ws_size,
                              hipStream_t stream) {
    const float* x      = (const float*)d_in[0];
    const int*   ei     = (const int*)d_in[1];
    const float* peW    = (const float*)d_in[3];
    const float* peb    = (const float*)d_in[4];

    const float* l_pW[2]   = {(const float*)d_in[5],  (const float*)d_in[17]};
    const float* l_pas[2]  = {(const float*)d_in[6],  (const float*)d_in[18]};
    const float* l_pad[2]  = {(const float*)d_in[7],  (const float*)d_in[19]};
    const float* l_posW[2] = {(const float*)d_in[8],  (const float*)d_in[20]};
    const float* l_posb[2] = {(const float*)d_in[9],  (const float*)d_in[21]};
    const float* l_dW[2]   = {(const float*)d_in[10], (const float*)d_in[22]};
    const float* l_das[2]  = {(const float*)d_in[11], (const float*)d_in[23]};
    const float* l_dad[2]  = {(const float*)d_in[12], (const float*)d_in[24]};
    const float* l_fW[2]   = {(const float*)d_in[13], (const float*)d_in[25]};
    const float* l_fb[2]   = {(const float*)d_in[14], (const float*)d_in[26]};
    const float* l_g[2]    = {(const float*)d_in[15], (const float*)d_in[27]};
    const float* l_b[2]    = {(const float*)d_in[16], (const float*)d_in[28]};
    const float* res_W  = (const float*)d_in[29];
    const float* res_b  = (const float*)d_in[30];
    const float* task_W = (const float*)d_in[31];
    const float* task_b = (const float*)d_in[32];

    float* ws = (float*)d_ws;
    float* spart   = ws + OFF_SPART;           // [BF_BLOCKS][128] stats partials
    float* pe_ws   = ws + OFF_PEWS;
    float* stats1  = ws + OFF_STAT1;
    float* wfrag   = ws + OFF_WFRAG;           // 2 x 4096 uints (fW bf16 fragments)
    float* wfrag2  = ws + OFF_WF2;             // 2 x 4096 uints (Wp/Wd bf16 fragments)
    float* pooled  = ws + OFF_POOL;            // [100][64]
    float* pooledF0= ws + OFF_POOL + 6400;     // [100][64]
    unsigned* hl   = (unsigned*)(ws + OFF_HL);    // bf16 [N][128] = [N][64] uints
    unsigned* cat_bf = (unsigned*)(ws + OFF_CAT); // bf16 [N][128] = [N][64] uints
    float* F0      = ws + OFF_F0;
    float* F1      = ws + OFF_F1;
    float* sps_p   = ws + OFF_SPSP;
    float* sps_d   = ws + OFF_SPSD;
    float2* dpd    = (float2*)(ws + OFF_DPD);
    float* stats0  = ws + OFF_STATS;
    int*   csr_off    = (int*)(ws + OFF_CSR);
    int*   sorted_src = (int*)(ws + OFF_SRT);
    float* out = (float*)d_out;

    const int NODE_BLOCKS = (N_NODES + 3) / 4;      // 25000
    const int GEMM_BLOCKS = (N_NODES + 63) / 64;    // 1563
    const int PB_BLOCKS   = N_GRAPHS * PB_PER_GRAPH; // 500

    sort_prep<<<N_GRAPHS + 4, 1024, 0, stream>>>(ei, csr_off, sorted_src,
        peW, peb, l_pW[0], l_dW[0], l_pW[1], l_dW[1], l_fW[0], l_fW[1],
        pe_ws, (uint4*)wfrag, (uint4*)wfrag2, pooled, stats0, stats1);

    // ----- layer 0 -----
    gemm_dual_mfma<true, false><<<GEMM_BLOCKS, 256, 0, stream>>>(x, (const unsigned*)wfrag2, pe_ws,
        l_pas[0], l_pad[0], l_das[0], l_dad[0], l_posW[0], l_posb[0],
        stats0, l_g[0], l_b[0], pooledF0,
        hl, sps_p, sps_d, dpd);
    gat_fused<<<NODE_BLOCKS, 256, 0, stream>>>(hl, sps_p, sps_d, dpd, csr_off, sorted_src, cat_bf);
    gemm_mfma_bf<<<BF_BLOCKS, 256, 0, stream>>>(cat_bf, (const unsigned*)wfrag,
                                                l_fb[0], F0, spart);
    reduce_stats<<<16, 128, 0, stream>>>(spart, stats0, BF_BLOCKS);

    // ----- layer 1 (BN+ELU+pool of F0 folded into the A-load) -----
    gemm_dual_mfma<false, true><<<GEMM_BLOCKS, 256, 0, stream>>>(F0, (const unsigned*)wfrag2 + 4096, pe_ws,
        l_pas[1], l_pad[1], l_das[1], l_dad[1], l_posW[1], l_posb[1],
        stats0, l_g[0], l_b[0], pooledF0,
        hl, sps_p, sps_d, dpd);
    gat_fused<<<NODE_BLOCKS, 256, 0, stream>>>(hl, sps_p, sps_d, dpd, csr_off, sorted_src, cat_bf);
    gemm_mfma_bf<<<BF_BLOCKS, 256, 0, stream>>>(cat_bf, (const unsigned*)wfrag + 4096,
                                                l_fb[1], F1, spart);
    reduce_stats<<<16, 128, 0, stream>>>(spart, stats1, BF_BLOCKS);
    pool_bn<<<PB_BLOCKS, 256, 0, stream>>>(F1, stats1, l_g[1], l_b[1], pooled);

    // ----- task head (residual folded via pooled F0) + diversity loss -----
    task_head<<<N_GRAPHS, 64, 0, stream>>>(pooled, pooledF0, res_W, res_b,
                                           task_W, task_b, out);
    div_loss<<<1, 256, 0, stream>>>(l_dW[0], l_dW[1], out + 1000);
}